// Round 6
// baseline (4432.037 us; speedup 1.0000x reference)
//
#include <hip/hip_runtime.h>
#include <math.h>

#define NE 1000000
#define DD 128
#define TWOD 256
#define H1C 256
#define H2C 128
#define EB 64
#define LDW 260          // padded LDS row stride (floats): rows hit disjoint banks
#define EPSLN 1e-5f

typedef float f32x2 __attribute__((ext_vector_type(2)));
typedef float f32x4 __attribute__((ext_vector_type(4)));

#define LO2(q) __builtin_shufflevector((q), (q), 0, 1)
#define HI2(q) __builtin_shufflevector((q), (q), 2, 3)

// c += broadcast(x.lo) * w
__device__ __forceinline__ void pk_fma_b0(f32x2& c, f32x2 x, f32x2 w) {
    asm("v_pk_fma_f32 %0, %1, %2, %0 op_sel:[0,0,0] op_sel_hi:[0,1,1]"
        : "+v"(c) : "v"(x), "v"(w));
}
// c += broadcast(x.hi) * w
__device__ __forceinline__ void pk_fma_b1(f32x2& c, f32x2 x, f32x2 w) {
    asm("v_pk_fma_f32 %0, %1, %2, %0 op_sel:[1,0,0] op_sel_hi:[1,1,1]"
        : "+v"(c) : "v"(x), "v"(w));
}

// GEMM1: one k step, 4 rows x 8 col-pairs (16 cols), broadcast half via XHALF/PKF
#define G1_K(KIDX, XHALF, PKF) do {                                            \
    const float* wp_ = w1p + (KIDX) * H1C;                                     \
    f32x4 w0_ = *(const f32x4*)(wp_);                                          \
    f32x4 w1_ = *(const f32x4*)(wp_ + 4);                                      \
    f32x4 w2_ = *(const f32x4*)(wp_ + 8);                                      \
    f32x4 w3_ = *(const f32x4*)(wp_ + 12);                                     \
    f32x2 p0_ = LO2(w0_), p1_ = HI2(w0_), p2_ = LO2(w1_), p3_ = HI2(w1_);      \
    f32x2 p4_ = LO2(w2_), p5_ = HI2(w2_), p6_ = LO2(w3_), p7_ = HI2(w3_);      \
    _Pragma("unroll") for (int i_ = 0; i_ < 4; ++i_) {                         \
        f32x2 xh_ = XHALF(xq[i_]);                                             \
        PKF(acc1[i_][0], xh_, p0_); PKF(acc1[i_][1], xh_, p1_);                \
        PKF(acc1[i_][2], xh_, p2_); PKF(acc1[i_][3], xh_, p3_);                \
        PKF(acc1[i_][4], xh_, p4_); PKF(acc1[i_][5], xh_, p5_);                \
        PKF(acc1[i_][6], xh_, p6_); PKF(acc1[i_][7], xh_, p7_);                \
    }                                                                          \
} while (0)

// GEMM2: one k step, 4 rows x 4 col-pairs (8 cols)
#define G2_K(KIDX, XHALF, PKF) do {                                            \
    const float* wp_ = w2p + (KIDX) * H2C;                                     \
    f32x4 w0_ = *(const f32x4*)(wp_);                                          \
    f32x4 w1_ = *(const f32x4*)(wp_ + 4);                                      \
    f32x2 p0_ = LO2(w0_), p1_ = HI2(w0_), p2_ = LO2(w1_), p3_ = HI2(w1_);      \
    _Pragma("unroll") for (int i_ = 0; i_ < 4; ++i_) {                         \
        f32x2 xh_ = XHALF(xq[i_]);                                             \
        PKF(acc2[i_][0], xh_, p0_); PKF(acc2[i_][1], xh_, p1_);                \
        PKF(acc2[i_][2], xh_, p2_); PKF(acc2[i_][3], xh_, p3_);                \
    }                                                                          \
} while (0)

__global__ __launch_bounds__(256, 2)
void decoder_fused(const float* __restrict__ nodes,
                   const float* __restrict__ nbrs,
                   const int*   __restrict__ eidx,
                   const float* __restrict__ g0, const float* __restrict__ be0,
                   const float* __restrict__ W1, const float* __restrict__ b1,
                   const float* __restrict__ g1, const float* __restrict__ be1,
                   const float* __restrict__ W2, const float* __restrict__ b2,
                   const float* __restrict__ g2, const float* __restrict__ be2,
                   const float* __restrict__ Wp, const float* __restrict__ bp,
                   const float* __restrict__ Ww, const float* __restrict__ bw,
                   const float* __restrict__ wnode, const float* __restrict__ wnbr,
                   float* __restrict__ out)
{
    __shared__ __align__(16) float xb[EB][LDW];   // ~66.6 KB; rows 16wv..16wv+15 private to wave wv
    __shared__ float nbsim[EB];

    const int t    = threadIdx.x;
    const int wv   = t >> 6;      // wave 0..3
    const int lane = t & 63;
    const int grp  = lane >> 4;   // 0..3 (16-lane group)
    const int gl   = lane & 15;   // 0..15
    const int e0   = blockIdx.x * EB;
    const int r0   = wv * 16 + grp * 4;   // this thread's 4 rows

    // ------- Stage 1: gather + combined + LN0 + nbrs_sim (4 edges/round) ----
    // 16 lanes per edge, lane covers node-dims d0..d0+7.
    // Reduction tree emulates old 64-wide butterfly bit-exactly:
    // in-lane = old lanes 4gl..4gl+3, levels m=1,2 in-lane, m=4..32 -> shfl 1,2,4,8.
    {
        const int d0 = gl * 8;
        const f32x4 g0s0 = *(const f32x4*)(g0  + d0);
        const f32x4 g0s1 = *(const f32x4*)(g0  + d0 + 4);
        const f32x4 g0p0 = *(const f32x4*)(g0  + DD + d0);
        const f32x4 g0p1 = *(const f32x4*)(g0  + DD + d0 + 4);
        const f32x4 e0s0 = *(const f32x4*)(be0 + d0);
        const f32x4 e0s1 = *(const f32x4*)(be0 + d0 + 4);
        const f32x4 e0p0 = *(const f32x4*)(be0 + DD + d0);
        const f32x4 e0p1 = *(const f32x4*)(be0 + DD + d0 + 4);
        #pragma unroll
        for (int rr = 0; rr < 4; ++rr) {
            const int el = wv * 16 + rr * 4 + grp;
            const int e  = e0 + el;
            const int u  = eidx[e];
            const int v  = eidx[NE + e];
            const f32x4 nu0 = *(const f32x4*)(nodes + u * DD + d0);
            const f32x4 nu1 = *(const f32x4*)(nodes + u * DD + d0 + 4);
            const f32x4 nv0 = *(const f32x4*)(nodes + v * DD + d0);
            const f32x4 nv1 = *(const f32x4*)(nodes + v * DD + d0 + 4);
            const f32x4 bu0 = *(const f32x4*)(nbrs  + u * DD + d0);
            const f32x4 bu1 = *(const f32x4*)(nbrs  + u * DD + d0 + 4);
            const f32x4 bv0 = *(const f32x4*)(nbrs  + v * DD + d0);
            const f32x4 bv1 = *(const f32x4*)(nbrs  + v * DD + d0 + 4);
            float s[8], p[8], bu[8], bv[8];
            #pragma unroll
            for (int j = 0; j < 4; ++j) {
                s[j]     = nu0[j] + nv0[j];  p[j]     = nu0[j] * nv0[j];
                s[4 + j] = nu1[j] + nv1[j];  p[4 + j] = nu1[j] * nv1[j];
                bu[j] = bu0[j]; bu[4 + j] = bu1[j];
                bv[j] = bv0[j]; bv[4 + j] = bv1[j];
            }
            // old-lane partials jj=0..3 (dims 2jj, 2jj+1), exact old expressions
            float ps_[4], pss_[4], pd_[4];
            #pragma unroll
            for (int jj = 0; jj < 4; ++jj) {
                const float sx = s[2*jj], sy = s[2*jj+1];
                const float px = p[2*jj], py = p[2*jj+1];
                ps_[jj]  = ((sx + sy) + px) + py;
                pss_[jj] = ((sx*sx + sy*sy) + px*px) + py*py;
                pd_[jj]  = bu[2*jj]*bv[2*jj] + bu[2*jj+1]*bv[2*jj+1];
            }
            // in-lane levels m=1, m=2
            float ps  = (ps_[0]  + ps_[1])  + (ps_[2]  + ps_[3]);
            float pss = (pss_[0] + pss_[1]) + (pss_[2] + pss_[3]);
            float pd  = (pd_[0]  + pd_[1])  + (pd_[2]  + pd_[3]);
            // remaining levels (old m=4,8,16,32) over 16 lanes
            #pragma unroll
            for (int m = 1; m < 16; m <<= 1) {
                ps  += __shfl_xor(ps,  m, 16);
                pss += __shfl_xor(pss, m, 16);
                pd  += __shfl_xor(pd,  m, 16);
            }
            const float mu  = ps  * (1.0f / 256.0f);
            const float var = pss * (1.0f / 256.0f) - mu * mu;
            const float inv = 1.0f / sqrtf(var + EPSLN);
            f32x4 os0, os1, op0, op1;
            #pragma unroll
            for (int j = 0; j < 4; ++j) {
                os0[j] = (s[j]     - mu) * inv * g0s0[j] + e0s0[j];
                os1[j] = (s[4 + j] - mu) * inv * g0s1[j] + e0s1[j];
                op0[j] = (p[j]     - mu) * inv * g0p0[j] + e0p0[j];
                op1[j] = (p[4 + j] - mu) * inv * g0p1[j] + e0p1[j];
            }
            *(f32x4*)&xb[el][d0]          = os0;
            *(f32x4*)&xb[el][d0 + 4]      = os1;
            *(f32x4*)&xb[el][DD + d0]     = op0;
            *(f32x4*)&xb[el][DD + d0 + 4] = op1;
            if (gl == 0) nbsim[el] = pd;
        }
    }
    __builtin_amdgcn_wave_barrier();   // fence: stage-1 writes before GEMM1 reads

    // ------- GEMM1: [16,256]@[256,256] per wave; 4 rows x 16 cols/lane ------
    f32x2 acc1[4][8];
    #pragma unroll
    for (int i = 0; i < 4; ++i)
        #pragma unroll
        for (int pp = 0; pp < 8; ++pp) acc1[i][pp] = f32x2{0.0f, 0.0f};

    const int c1 = gl * 16;
    {
        const float* __restrict__ w1p = W1 + c1;
        #pragma unroll 2
        for (int k0 = 0; k0 < TWOD; k0 += 4) {
            f32x4 xq[4];
            #pragma unroll
            for (int i = 0; i < 4; ++i) xq[i] = *(const f32x4*)&xb[r0 + i][k0];
            G1_K(k0 + 0, LO2, pk_fma_b0);
            G1_K(k0 + 1, LO2, pk_fma_b1);
            G1_K(k0 + 2, HI2, pk_fma_b0);
            G1_K(k0 + 3, HI2, pk_fma_b1);
        }
    }
    __builtin_amdgcn_wave_barrier();   // fence: GEMM1 reads before LN1 writes

    // ------- bias + LN1 + ReLU, write h1 back (own rows/cols) ----------------
    // tree: in-lane serial sums over old col-groups 2gl (v[0..7]) and 2gl+1
    // (v[8..15]), then old m=1 in-lane, old m=2..16 -> shfl 1,2,4,8 (width 16)
    {
        const f32x4 b1q[4] = { *(const f32x4*)(b1 + c1),      *(const f32x4*)(b1 + c1 + 4),
                               *(const f32x4*)(b1 + c1 + 8),  *(const f32x4*)(b1 + c1 + 12) };
        const f32x4 g1q[4] = { *(const f32x4*)(g1 + c1),      *(const f32x4*)(g1 + c1 + 4),
                               *(const f32x4*)(g1 + c1 + 8),  *(const f32x4*)(g1 + c1 + 12) };
        const f32x4 e1q[4] = { *(const f32x4*)(be1 + c1),     *(const f32x4*)(be1 + c1 + 4),
                               *(const f32x4*)(be1 + c1 + 8), *(const f32x4*)(be1 + c1 + 12) };
        #pragma unroll
        for (int i = 0; i < 4; ++i) {
            float v[16];
            #pragma unroll
            for (int pp = 0; pp < 8; ++pp) {
                v[2*pp]     = acc1[i][pp].x + b1q[pp >> 1][(pp & 1) * 2];
                v[2*pp + 1] = acc1[i][pp].y + b1q[pp >> 1][(pp & 1) * 2 + 1];
            }
            float sA = 0.0f, ssA = 0.0f, sB = 0.0f, ssB = 0.0f;
            #pragma unroll
            for (int j = 0; j < 8; ++j) { sA += v[j]; ssA += v[j] * v[j]; }
            #pragma unroll
            for (int j = 8; j < 16; ++j) { sB += v[j]; ssB += v[j] * v[j]; }
            float s = sA + sB, ss = ssA + ssB;
            #pragma unroll
            for (int m = 1; m < 16; m <<= 1) {
                s  += __shfl_xor(s,  m, 16);
                ss += __shfl_xor(ss, m, 16);
            }
            const float mu  = s  * (1.0f / 256.0f);
            const float var = ss * (1.0f / 256.0f) - mu * mu;
            const float inv = 1.0f / sqrtf(var + EPSLN);
            f32x4 o[4];
            #pragma unroll
            for (int j = 0; j < 16; ++j)
                o[j >> 2][j & 3] = fmaxf(0.0f, (v[j] - mu) * inv * g1q[j >> 2][j & 3] + e1q[j >> 2][j & 3]);
            *(f32x4*)&xb[r0 + i][c1]      = o[0];
            *(f32x4*)&xb[r0 + i][c1 + 4]  = o[1];
            *(f32x4*)&xb[r0 + i][c1 + 8]  = o[2];
            *(f32x4*)&xb[r0 + i][c1 + 12] = o[3];
        }
    }
    __builtin_amdgcn_wave_barrier();   // fence: LN1 writes before GEMM2 reads

    // ------- GEMM2: [16,256]@[256,128] per wave; 4 rows x 8 cols/lane --------
    f32x2 acc2[4][4];
    #pragma unroll
    for (int i = 0; i < 4; ++i)
        #pragma unroll
        for (int pp = 0; pp < 4; ++pp) acc2[i][pp] = f32x2{0.0f, 0.0f};

    const int c2 = gl * 8;
    {
        const float* __restrict__ w2p = W2 + c2;
        #pragma unroll 2
        for (int k0 = 0; k0 < TWOD; k0 += 4) {
            f32x4 xq[4];
            #pragma unroll
            for (int i = 0; i < 4; ++i) xq[i] = *(const f32x4*)&xb[r0 + i][k0];
            G2_K(k0 + 0, LO2, pk_fma_b0);
            G2_K(k0 + 1, LO2, pk_fma_b1);
            G2_K(k0 + 2, HI2, pk_fma_b0);
            G2_K(k0 + 3, HI2, pk_fma_b1);
        }
    }

    // ------- bias + LN2 + ReLU + heads + outputs -----------------------------
    {
        const f32x4 b2a = *(const f32x4*)(b2  + c2), b2b = *(const f32x4*)(b2  + c2 + 4);
        const f32x4 g2a = *(const f32x4*)(g2  + c2), g2b = *(const f32x4*)(g2  + c2 + 4);
        const f32x4 e2a = *(const f32x4*)(be2 + c2), e2b = *(const f32x4*)(be2 + c2 + 4);
        const f32x4 wpa = *(const f32x4*)(Wp  + c2), wpb = *(const f32x4*)(Wp  + c2 + 4);
        const f32x4 wwa = *(const f32x4*)(Ww  + c2), wwb = *(const f32x4*)(Ww  + c2 + 4);
        const float ww128 = Ww[DD];
        const float bpv = bp[0], bwv = bw[0];
        const float wn = wnode[0], wbr = wnbr[0];
        #pragma unroll
        for (int i = 0; i < 4; ++i) {
            float v[8];
            #pragma unroll
            for (int pp = 0; pp < 4; ++pp) {
                const f32x4 bq = (pp < 2) ? b2a : b2b;
                v[2*pp]     = acc2[i][pp].x + bq[(pp & 1) * 2];
                v[2*pp + 1] = acc2[i][pp].y + bq[(pp & 1) * 2 + 1];
            }
            float sA  = ((v[0] + v[1]) + v[2]) + v[3];
            float sB  = ((v[4] + v[5]) + v[6]) + v[7];
            float ssA = ((v[0]*v[0] + v[1]*v[1]) + v[2]*v[2]) + v[3]*v[3];
            float ssB = ((v[4]*v[4] + v[5]*v[5]) + v[6]*v[6]) + v[7]*v[7];
            float s = sA + sB, ss = ssA + ssB;
            #pragma unroll
            for (int m = 1; m < 16; m <<= 1) {
                s  += __shfl_xor(s,  m, 16);
                ss += __shfl_xor(ss, m, 16);
            }
            const float mu  = s  * (1.0f / 128.0f);
            const float var = ss * (1.0f / 128.0f) - mu * mu;
            const float inv = 1.0f / sqrtf(var + EPSLN);
            float h[8];
            #pragma unroll
            for (int j = 0; j < 4; ++j) {
                h[j]     = fmaxf(0.0f, (v[j]     - mu) * inv * g2a[j] + e2a[j]);
                h[4 + j] = fmaxf(0.0f, (v[4 + j] - mu) * inv * g2b[j] + e2b[j]);
            }
            float pdot = (((h[0]*wpa[0] + h[1]*wpa[1]) + h[2]*wpa[2]) + h[3]*wpa[3])
                       + (((h[4]*wpb[0] + h[5]*wpb[1]) + h[6]*wpb[2]) + h[7]*wpb[3]);
            float wdot = (((h[0]*wwa[0] + h[1]*wwa[1]) + h[2]*wwa[2]) + h[3]*wwa[3])
                       + (((h[4]*wwb[0] + h[5]*wwb[1]) + h[6]*wwb[2]) + h[7]*wwb[3]);
            #pragma unroll
            for (int m = 1; m < 16; m <<= 1) {
                pdot += __shfl_xor(pdot, m, 16);
                wdot += __shfl_xor(wdot, m, 16);
            }
            if (gl == 0) {
                const int e  = e0 + r0 + i;
                const float ns   = nbsim[r0 + i];
                const float nc   = (pdot + bpv) * wn;
                const float nbc  = ns * wbr;
                const float prob = nc + nbc;
                out[e]          = prob;
                out[NE + e]     = fmaxf(0.0f, wdot + ns * ww128 + bwv);
                out[2 * NE + e] = nc / (prob + 1e-8f);
            }
        }
    }
}

extern "C" void kernel_launch(void* const* d_in, const int* in_sizes, int n_in,
                              void* d_out, int out_size, void* d_ws, size_t ws_size,
                              hipStream_t stream) {
    const float* nodes = (const float*)d_in[0];
    const float* nbrs  = (const float*)d_in[1];
    const int*   eidx  = (const int*)d_in[2];
    const float* g0    = (const float*)d_in[3];
    const float* be0   = (const float*)d_in[4];
    const float* W1    = (const float*)d_in[5];
    const float* b1    = (const float*)d_in[6];
    const float* g1    = (const float*)d_in[7];
    const float* be1   = (const float*)d_in[8];
    const float* W2    = (const float*)d_in[9];
    const float* b2    = (const float*)d_in[10];
    const float* g2    = (const float*)d_in[11];
    const float* be2   = (const float*)d_in[12];
    const float* Wp    = (const float*)d_in[13];
    const float* bp    = (const float*)d_in[14];
    const float* Ww    = (const float*)d_in[15];
    const float* bw    = (const float*)d_in[16];
    const float* wnode = (const float*)d_in[17];
    const float* wnbr  = (const float*)d_in[18];
    float* out = (float*)d_out;

    dim3 grid(NE / EB), block(256);
    decoder_fused<<<grid, block, 0, stream>>>(nodes, nbrs, eidx, g0, be0,
                                              W1, b1, g1, be1, W2, b2, g2, be2,
                                              Wp, bp, Ww, bw, wnode, wnbr, out);
}